// Round 14
// baseline (236.951 us; speedup 1.0000x reference)
//
#include <hip/hip_runtime.h>
#include <math.h>

// IDMPNN fused forward — R14: R13 + epilogue register diet + (192,3).
// R13 lesson: the ~67us bench-vs-main residue is harness-fixed (prep fix was
// neutral). Main (~133us) is latency-bound at ~2 waves/SIMD; suspected cause:
// unified-file total (arch+acc) > 170. R11 showed (192,3) squeezes the
// allocator to ~84 arch; the old epilogue held v[2][16]+tbh[2][2][2] = 64 live
// regs and spilled. This version restructures GEMM-C'/LN fully per-(in_,ch):
// B-frags read per chain (8 regs), one v[16] live, W2 frags reloaded (L1-hot).
// Peak live ~80-90 -> fits (192,3)'s budget -> 3 waves/SIMD, 4 blocks/CU,
// 24 concurrent chains (+50%). Math bit-identical (same accumulation order).

#define NBATCH 64
#define NM 32
#define NS 32
#define KSUB 3
#define HID 64
#define NLAYER 4
#define PP 6
#define STOT (NBATCH * NS)

// d_ws: fp16 weight planes (ushort offsets), then byte offsets
#define W1F 0            // [l][dout][din] 16384
#define W2F 16384
#define S1F 32768        // planes end at ushort 36864 = byte 73728
#define GMAX_BYTE 73728  // uint[64*64]
#define CNT_BYTE  90112  // uint[64]
#define S2WT_BYTE 90368  // float[64*64]

// LDS row strides (ushorts)
#define SH 68    // HB rows (32 x 64 fp16 + pad)
#define SG 36    // GB rows (64 x 32 fp16 + pad)
#define WBU 2304 // per-chain buffer ushorts (4608B): max(32*68, 64*36)

typedef _Float16 f16x8 __attribute__((ext_vector_type(8)));
typedef __fp16 fp16x2 __attribute__((ext_vector_type(2)));   // cvt_pkrtz return
typedef float f32x4 __attribute__((ext_vector_type(4)));

#define MFMA16(a, b, c) __builtin_amdgcn_mfma_f32_16x16x32_f16(a, b, c, 0, 0, 0)

__constant__ int c_perm[KSUB][PP] = {
    {0, 0, 1, 1, 2, 2},
    {1, 2, 0, 2, 0, 1},
    {2, 1, 2, 0, 1, 0}
};

__device__ __forceinline__ unsigned pk2rtz(float a, float b) {
    union { fp16x2 h; unsigned u; } x;
    x.h = __builtin_amdgcn_cvt_pkrtz(a, b);
    return x.u;
}
__device__ __forceinline__ uint2 pk4rtz(float a, float b, float c, float d) {
    return make_uint2(pk2rtz(a, b), pk2rtz(c, d));
}
__device__ __forceinline__ f16x8 frd(const unsigned short* p) {   // LDS, 8B-aligned
    union { struct { uint2 a, b; } u; f16x8 f; } x;
    x.u.a = *(const uint2*)p;
    x.u.b = *(const uint2*)(p + 4);
    return x.f;
}
__device__ __forceinline__ f16x8 gfrd(const unsigned short* p) {  // global, 16B-aligned
    union { uint4 u; f16x8 f; } x;
    x.u = *(const uint4*)p;
    return x.f;
}
__device__ __forceinline__ float2 upk2(unsigned u) {
    union { unsigned u; _Float16 h[2]; } x; x.u = u;
    return make_float2((float)x.h[0], (float)x.h[1]);
}

// ---- prep v2: coalesced LDS tile transpose (R13, kept) ----
extern "C" __global__ void idmpnn_prep(const float* __restrict__ w1,
                                       const float* __restrict__ w2,
                                       const float* __restrict__ s1w,
                                       const float* __restrict__ s2w,
                                       char* __restrict__ ws)
{
    __shared__ float tile[64][65];
    unsigned short* wsu = (unsigned short*)ws;
    const int bid = blockIdx.x, t = threadIdx.x;   // 256 threads

    if (bid < 9) {
        const float* src;
        unsigned short* dst;
        if (bid < 4)      { src = w1 + bid * 4096;       dst = wsu + W1F + bid * 4096; }
        else if (bid < 8) { src = w2 + (bid - 4) * 4096; dst = wsu + W2F + (bid - 4) * 4096; }
        else              { src = s1w;                   dst = wsu + S1F; }
#pragma unroll
        for (int k = 0; k < 16; ++k) {
            int lin = k * 256 + t;                 // coalesced read
            tile[lin & 63][lin >> 6] = src[lin];   // tile[c][r] = src[r][c]
        }
        __syncthreads();
#pragma unroll
        for (int k = 0; k < 16; ++k) {
            int lin = k * 256 + t;                 // coalesced write
            union { _Float16 h; unsigned short u; } cv;
            cv.h = (_Float16)tile[lin >> 6][lin & 63];  // RNE
            dst[lin] = cv.u;
        }
    } else if (bid == 9) {
        float* dstf = (float*)(ws + S2WT_BYTE);
#pragma unroll
        for (int k = 0; k < 16; ++k) {
            int lin = k * 256 + t;
            tile[lin & 63][lin >> 6] = s2w[lin];
        }
        __syncthreads();
#pragma unroll
        for (int k = 0; k < 16; ++k) {
            int lin = k * 256 + t;
            dstf[lin] = tile[lin >> 6][lin & 63];
        }
    } else if (bid == 10) {
        unsigned* g = (unsigned*)(ws + GMAX_BYTE);
#pragma unroll
        for (int k = 0; k < 16; ++k) g[k * 256 + t] = 0u;
    } else {
        if (t < 64) ((unsigned*)(ws + CNT_BYTE))[t] = 0u;
    }
}

extern "C" __global__ void __launch_bounds__(192, 3)
idmpnn_main(const int* __restrict__ xg, const float* __restrict__ subadj,
            const int* __restrict__ subgs, const int* __restrict__ num_node,
            const float* __restrict__ idemb, const float* __restrict__ node_emb,
            const float* __restrict__ b1g, const float* __restrict__ b2g,
            const float* __restrict__ lngm, const float* __restrict__ lnbm,
            const float* __restrict__ s1bm, const float* __restrict__ s2bm,
            const float* __restrict__ outw, const float* __restrict__ outb,
            const unsigned short* __restrict__ wsf, const float* __restrict__ s2wt,
            unsigned* __restrict__ gmax, unsigned* __restrict__ cnt,
            float* __restrict__ out)
{
    // 27648 + 768 + 4096 + 256 = 32768 B LDS
    __shared__ unsigned short WB[6 * WBU];   // [perm] HB/GB views + final dump
    __shared__ float idS[KSUB * 64];
    __shared__ float prm[NLAYER * 4 * 64];   // b1,b2,g,be per layer
    __shared__ float HSf[HID];

    const int s = blockIdx.x, b = s >> 5;    // one subgraph per block
    const int tid = threadIdx.x;
    const int w = tid / 64, lane = tid & 63; // w = 0..2; wave owns perms 2w,2w+1
    const int c = lane & 15, q = lane >> 4;

    for (int t = tid; t < NLAYER * 4 * 64; t += 192) {
        int l = t >> 8, r2 = t & 255, set = r2 >> 6, d = r2 & 63;
        const float* src = (set == 0) ? b1g : (set == 1) ? b2g : (set == 2) ? lngm : lnbm;
        prm[t] = src[l * HID + d];
    }
    if (tid < KSUB * 64) idS[tid] = idemb[tid];

    const int nd0 = subgs[s * KSUB + 0];
    const int nd1 = subgs[s * KSUB + 1];
    const int nd2 = subgs[s * KSUB + 2];
    const int nn = num_node[b];
    const int zi0 = xg[b * NM + c];
    const int zi1 = xg[b * NM + 16 + c];

    // adjacency fp16 B-frags: lane holds adj[i=in*16+c][j=8q+jj], regs
    f16x8 adjf[2];
#pragma unroll
    for (int in_ = 0; in_ < 2; ++in_) {
        const float* ap = subadj + (size_t)b * NM * NM + (in_ * 16 + c) * NM + 8 * q;
        float4 f0 = *(const float4*)ap;
        float4 f1 = *(const float4*)(ap + 4);
        union { struct { uint2 a, b; } u; f16x8 f; } x;
        x.u.a = pk4rtz(f0.x, f0.y, f0.z, f0.w);
        x.u.b = pk4rtz(f1.x, f1.y, f1.z, f1.w);
        adjf[in_] = x.f;
    }

    __syncthreads();

    // chain ch (0,1) = perm w*2+ch; private buffer per chain
    unsigned short* wbc[2] = { WB + (w * 2 + 0) * WBU, WB + (w * 2 + 1) * WBU };

    // h packed 2xfp16: hpk[ch][in*8+dm*2+g2] = h[i=in*16+c][d=dm*16+4q+2g2+{0,1}]
    unsigned hpk[2][16];
#pragma unroll
    for (int in_ = 0; in_ < 2; ++in_) {
        int i = in_ * 16 + c;
        int z = in_ ? zi1 : zi0;
        int pid[2];
#pragma unroll
        for (int ch = 0; ch < 2; ++ch) {
            int p = w * 2 + ch;
            pid[ch] = (i == nd0) ? c_perm[0][p] : (i == nd1) ? c_perm[1][p]
                      : (i == nd2) ? c_perm[2][p] : -1;
        }
#pragma unroll
        for (int dm = 0; dm < 4; ++dm) {
            float4 e4 = *(const float4*)(node_emb + (size_t)z * HID + dm * 16 + 4 * q);
#pragma unroll
            for (int ch = 0; ch < 2; ++ch) {
                float4 v = e4;
                if (pid[ch] >= 0) {
                    float4 f4 = *(const float4*)&idS[pid[ch] * 64 + dm * 16 + 4 * q];
                    v.x *= f4.x; v.y *= f4.y; v.z *= f4.z; v.w *= f4.w;
                }
                uint2 u = pk4rtz(v.x, v.y, v.z, v.w);
                hpk[ch][in_ * 8 + dm * 2 + 0] = u.x;
                hpk[ch][in_ * 8 + dm * 2 + 1] = u.y;
            }
        }
    }

#pragma unroll 1
    for (int l = 0; l < NLAYER; ++l) {
        // (1) h -> HB [i][d], both chains
#pragma unroll
        for (int ch = 0; ch < 2; ++ch)
#pragma unroll
            for (int in_ = 0; in_ < 2; ++in_)
#pragma unroll
                for (int dm = 0; dm < 4; ++dm)
                    *(uint2*)(wbc[ch] + (in_ * 16 + c) * SH + dm * 16 + 4 * q) =
                        make_uint2(hpk[ch][in_ * 8 + dm * 2], hpk[ch][in_ * 8 + dm * 2 + 1]);

        // (2) GEMM-A A-frags, both chains (preload all: GB write clobbers HB)
        f16x8 hah[2][2][2];
#pragma unroll
        for (int ch = 0; ch < 2; ++ch)
#pragma unroll
            for (int im = 0; im < 2; ++im)
#pragma unroll
                for (int ks = 0; ks < 2; ++ks)
                    hah[ch][im][ks] = frd(wbc[ch] + (im * 16 + c) * SH + ks * 32 + 8 * q);

        // (3+4) GEMM-A: g = h @ W1; write GB [d'][i] (weights shared)
#pragma unroll
        for (int jn = 0; jn < 4; ++jn) {
            const unsigned short* wp = wsf + W1F + (l * 64 + jn * 16 + c) * 64;
            f16x8 b0 = gfrd(wp + 8 * q);
            f16x8 b1 = gfrd(wp + 32 + 8 * q);
#pragma unroll
            for (int ch = 0; ch < 2; ++ch) {
                f32x4 g0 = {0.f, 0.f, 0.f, 0.f}, g1 = {0.f, 0.f, 0.f, 0.f};
                g0 = MFMA16(hah[ch][0][0], b0, g0);
                g0 = MFMA16(hah[ch][0][1], b1, g0);
                g1 = MFMA16(hah[ch][1][0], b0, g1);
                g1 = MFMA16(hah[ch][1][1], b1, g1);
                *(uint2*)(wbc[ch] + (jn * 16 + c) * SG + 4 * q)      = pk4rtz(g0[0], g0[1], g0[2], g0[3]);
                *(uint2*)(wbc[ch] + (jn * 16 + c) * SG + 16 + 4 * q) = pk4rtz(g1[0], g1[1], g1[2], g1[3]);
            }
        }

        // (5) GEMM-B A-frags
        f16x8 gah[2][4];
#pragma unroll
        for (int ch = 0; ch < 2; ++ch)
#pragma unroll
            for (int dm = 0; dm < 4; ++dm)
                gah[ch][dm] = frd(wbc[ch] + (dm * 16 + c) * SG + 8 * q);

        // (6+7) GEMM-B: t^T = g^T @ adjT; t -> HB with relu(+b1)
#pragma unroll
        for (int dm = 0; dm < 4; ++dm) {
            float4 b1v = *(const float4*)&prm[(l * 4 + 0) * 64 + dm * 16 + 4 * q];
#pragma unroll
            for (int ch = 0; ch < 2; ++ch) {
                f32x4 t0 = {0.f, 0.f, 0.f, 0.f}, t1 = {0.f, 0.f, 0.f, 0.f};
                t0 = MFMA16(gah[ch][dm], adjf[0], t0);
                t1 = MFMA16(gah[ch][dm], adjf[1], t1);
                *(uint2*)(wbc[ch] + c * SH + dm * 16 + 4 * q) =
                    pk4rtz(fmaxf(t0[0] + b1v.x, 0.f), fmaxf(t0[1] + b1v.y, 0.f),
                           fmaxf(t0[2] + b1v.z, 0.f), fmaxf(t0[3] + b1v.w, 0.f));
                *(uint2*)(wbc[ch] + (16 + c) * SH + dm * 16 + 4 * q) =
                    pk4rtz(fmaxf(t1[0] + b1v.x, 0.f), fmaxf(t1[1] + b1v.y, 0.f),
                           fmaxf(t1[2] + b1v.z, 0.f), fmaxf(t1[3] + b1v.w, 0.f));
            }
        }

        // (8+9+10) per (in_, ch): B-frags from HB, u^T = W2^T @ t^T, LN, relu,
        // residual. Restructured per-chain: one v[16] + 8 frag regs live
        // (was v[2][16] + tbh[2][2][2] = 64) — fits (192,3)'s ~84-arch budget.
        // W2 frags reloaded per chain (L1-hot, +24 16B loads/layer).
#pragma unroll
        for (int in_ = 0; in_ < 2; ++in_) {
#pragma unroll
            for (int ch = 0; ch < 2; ++ch) {
                f16x8 tb0 = frd(wbc[ch] + (in_ * 16 + c) * SH + 8 * q);
                f16x8 tb1 = frd(wbc[ch] + (in_ * 16 + c) * SH + 32 + 8 * q);
                float v[16];
                float s1 = 0.f, s2 = 0.f;
#pragma unroll
                for (int dm = 0; dm < 4; ++dm) {
                    const unsigned short* wp2 = wsf + W2F + (l * 64 + dm * 16 + c) * 64;
                    f16x8 a0 = gfrd(wp2 + 8 * q);
                    f16x8 a1 = gfrd(wp2 + 32 + 8 * q);
                    f32x4 u = {0.f, 0.f, 0.f, 0.f};
                    u = MFMA16(a0, tb0, u);
                    u = MFMA16(a1, tb1, u);
                    float4 b2v = *(const float4*)&prm[(l * 4 + 1) * 64 + dm * 16 + 4 * q];
                    const float* bb = (const float*)&b2v;
#pragma unroll
                    for (int r = 0; r < 4; ++r) {
                        float x = u[r] + bb[r];
                        v[dm * 4 + r] = x;
                        s1 += x;
                        s2 += x * x;
                    }
                }
                s1 += __shfl_xor(s1, 16, 64); s1 += __shfl_xor(s1, 32, 64);
                s2 += __shfl_xor(s2, 16, 64); s2 += __shfl_xor(s2, 32, 64);
                float mean = s1 * (1.0f / HID);
                float var  = s2 * (1.0f / HID) - mean * mean;
                float rs   = rsqrtf(var + 1e-5f);
#pragma unroll
                for (int dm = 0; dm < 4; ++dm) {
                    float4 gv4  = *(const float4*)&prm[(l * 4 + 2) * 64 + dm * 16 + 4 * q];
                    float4 bev4 = *(const float4*)&prm[(l * 4 + 3) * 64 + dm * 16 + 4 * q];
                    const float* gp = (const float*)&gv4;
                    const float* bp = (const float*)&bev4;
                    float y0 = fmaxf((v[dm * 4 + 0] - mean) * rs * gp[0] + bp[0], 0.f);
                    float y1 = fmaxf((v[dm * 4 + 1] - mean) * rs * gp[1] + bp[1], 0.f);
                    float y2 = fmaxf((v[dm * 4 + 2] - mean) * rs * gp[2] + bp[2], 0.f);
                    float y3 = fmaxf((v[dm * 4 + 3] - mean) * rs * gp[3] + bp[3], 0.f);
                    int i0 = in_ * 8 + dm * 2;
                    float2 h0 = upk2(hpk[ch][i0 + 0]);
                    float2 h1 = upk2(hpk[ch][i0 + 1]);
                    hpk[ch][i0 + 0] = pk2rtz(h0.x + y0, h0.y + y1);
                    hpk[ch][i0 + 1] = pk2rtz(h1.x + y2, h1.y + y3);
                }
            }
        }
    }

    // ---- dump final h (fp16 [i][d]) into per-chain buffers ----
#pragma unroll
    for (int ch = 0; ch < 2; ++ch)
#pragma unroll
        for (int in_ = 0; in_ < 2; ++in_)
#pragma unroll
            for (int dm = 0; dm < 4; ++dm)
                *(uint2*)(wbc[ch] + (in_ * 16 + c) * SH + dm * 16 + 4 * q) =
                    make_uint2(hpk[ch][in_ * 8 + dm * 2], hpk[ch][in_ * 8 + dm * 2 + 1]);
    __syncthreads();

    // ---- tail (wave 0): combine 6 perms, GEMM-D, colsum, set2, pooling ----
    if (w == 0) {
        f16x8 mah[2][2];
#pragma unroll
        for (int im = 0; im < 2; ++im) {
            float sc = ((im * 16 + c) < nn) ? (1.0f / PP) : 0.f;
#pragma unroll
            for (int ks = 0; ks < 2; ++ks) {
                int ro = (im * 16 + c) * SH + ks * 32 + 8 * q;
                float acc8[8];
#pragma unroll
                for (int j = 0; j < 8; ++j) acc8[j] = 0.f;
#pragma unroll
                for (int pv = 0; pv < 6; ++pv) {
                    f16x8 f = frd(WB + pv * WBU + ro);
#pragma unroll
                    for (int j = 0; j < 8; ++j) acc8[j] += (float)f[j];
                }
                f16x8 m;
#pragma unroll
                for (int j = 0; j < 8; ++j) m[j] = (_Float16)(acc8[j] * sc);
                mah[im][ks] = m;
            }
        }

        // GEMM-D: h1 = hm @ set1_W (m=i, n=dout)
        f32x4 hh[2][4];
#pragma unroll
        for (int im = 0; im < 2; ++im)
#pragma unroll
            for (int jn = 0; jn < 4; ++jn) hh[im][jn] = (f32x4){0.f, 0.f, 0.f, 0.f};
#pragma unroll
        for (int jn = 0; jn < 4; ++jn) {
            const unsigned short* sp = wsf + S1F + (jn * 16 + c) * 64;
            f16x8 b0 = gfrd(sp + 8 * q);
            f16x8 b1 = gfrd(sp + 32 + 8 * q);
#pragma unroll
            for (int im = 0; im < 2; ++im) {
                hh[im][jn] = MFMA16(mah[im][0], b0, hh[im][jn]);
                hh[im][jn] = MFMA16(mah[im][1], b1, hh[im][jn]);
            }
        }
        // colsum over all 32 rows (padded rows contribute relu(s1b), as ref)
#pragma unroll
        for (int jn = 0; jn < 4; ++jn) {
            float sb = s1bm[jn * 16 + c];
            float cs = 0.f;
#pragma unroll
            for (int im = 0; im < 2; ++im)
#pragma unroll
                for (int r = 0; r < 4; ++r)
                    cs += fmaxf(hh[im][jn][r] + sb, 0.f);
            cs += __shfl_xor(cs, 16, 64);
            cs += __shfl_xor(cs, 32, 64);
            if (q == 0) HSf[jn * 16 + c] = cs;
        }

        // h2 = relu(HS @ set2_W + s2b), lane = dout
        float acc = 0.f;
#pragma unroll
        for (int e4 = 0; e4 < 16; ++e4) {
            float4 wv = *(const float4*)&s2wt[lane * 64 + e4 * 4];
            float4 hv = *(const float4*)&HSf[e4 * 4];
            acc += hv.x * wv.x + hv.y * wv.y + hv.z * wv.z + hv.w * wv.w;
        }
        float h2 = fmaxf(acc + s2bm[lane], 0.f);

        // pooling fold: device-scope atomicMax (h2 >= 0: uint order == float order)
        atomicMax(&gmax[b * HID + lane], __float_as_uint(h2));
        __threadfence();
        unsigned old = 0;
        if (lane == 0) old = atomicAdd(&cnt[b], 1u);
        old = __shfl(old, 0, 64);
        if (old == NS - 1) {   // last of the 32 subgraph-writers of this graph
            __threadfence();
            unsigned mbits = atomicOr(&gmax[b * HID + lane], 0u);
            float v = __uint_as_float(mbits) * outw[lane];
#pragma unroll
            for (int off = 32; off > 0; off >>= 1) v += __shfl_xor(v, off, 64);
            if (lane == 0) out[b] = v + outb[0];
        }
    }
}

extern "C" void kernel_launch(void* const* d_in, const int* in_sizes, int n_in,
                              void* d_out, int out_size, void* d_ws, size_t ws_size,
                              hipStream_t stream)
{
    const int*   xg       = (const int*)d_in[0];
    const float* subadj   = (const float*)d_in[1];
    const int*   subgs    = (const int*)d_in[2];
    const int*   num_node = (const int*)d_in[3];
    const float* idemb    = (const float*)d_in[5];
    const float* node_emb = (const float*)d_in[6];
    const float* w1       = (const float*)d_in[7];
    const float* b1       = (const float*)d_in[8];
    const float* w2       = (const float*)d_in[9];
    const float* b2       = (const float*)d_in[10];
    const float* g        = (const float*)d_in[11];
    const float* be       = (const float*)d_in[12];
    const float* s1w      = (const float*)d_in[13];
    const float* s1b      = (const float*)d_in[14];
    const float* s2w      = (const float*)d_in[15];
    const float* s2b      = (const float*)d_in[16];
    const float* outw     = (const float*)d_in[17];
    const float* outb     = (const float*)d_in[18];

    char* ws = (char*)d_ws;
    unsigned short* wsf = (unsigned short*)ws;
    const float* s2wt = (const float*)(ws + S2WT_BYTE);
    unsigned* gmax = (unsigned*)(ws + GMAX_BYTE);
    unsigned* cnt  = (unsigned*)(ws + CNT_BYTE);

    idmpnn_prep<<<12, 256, 0, stream>>>(w1, w2, s1w, s2w, ws);
    idmpnn_main<<<STOT, 192, 0, stream>>>(xg, subadj, subgs, num_node,
                                          idemb, node_emb,
                                          b1, b2, g, be, s1b, s2b, outw, outb,
                                          wsf, s2wt, gmax, cnt, (float*)d_out);
}

// Round 15
// 208.328 us; speedup vs baseline: 1.1374x; 1.1374x over previous
//
#include <hip/hip_runtime.h>
#include <math.h>

// IDMPNN fused forward — R15 (final): R13 structure, (192,2), two chain-trims:
// (1) residual via v_pk_add_f16 (R9-verified numerics), (2) h->HB write fused
// into the epilogue (layer-0 init writes HB once; post-loop dump removed) —
// moves the write ~a full LN-tail earlier, hiding one ~150cyc stall/layer.
// Lessons burned in: min-waves>=3 always spills this kernel (R4/R6/R11/R14);
// K16 zero-LDS trades LDS latency for 2x MFMA issue at a net loss (R10);
// chain-count scaling is falsified (R12 12-chain beat R9 24-chain).

#define NBATCH 64
#define NM 32
#define NS 32
#define KSUB 3
#define HID 64
#define NLAYER 4
#define PP 6
#define STOT (NBATCH * NS)

// d_ws: fp16 weight planes (ushort offsets), then byte offsets
#define W1F 0            // [l][dout][din] 16384
#define W2F 16384
#define S1F 32768        // planes end at ushort 36864 = byte 73728
#define GMAX_BYTE 73728  // uint[64*64]
#define CNT_BYTE  90112  // uint[64]
#define S2WT_BYTE 90368  // float[64*64]

// LDS row strides (ushorts)
#define SH 68    // HB rows (32 x 64 fp16 + pad)
#define SG 36    // GB rows (64 x 32 fp16 + pad)
#define WBU 2304 // per-chain buffer ushorts (4608B): max(32*68, 64*36)

typedef _Float16 f16x8 __attribute__((ext_vector_type(8)));
typedef _Float16 f16x2 __attribute__((ext_vector_type(2)));
typedef __fp16 fp16x2 __attribute__((ext_vector_type(2)));   // cvt_pkrtz return
typedef float f32x4 __attribute__((ext_vector_type(4)));

#define MFMA16(a, b, c) __builtin_amdgcn_mfma_f32_16x16x32_f16(a, b, c, 0, 0, 0)

__constant__ int c_perm[KSUB][PP] = {
    {0, 0, 1, 1, 2, 2},
    {1, 2, 0, 2, 0, 1},
    {2, 1, 2, 0, 1, 0}
};

__device__ __forceinline__ unsigned pk2rtz(float a, float b) {
    union { fp16x2 h; unsigned u; } x;
    x.h = __builtin_amdgcn_cvt_pkrtz(a, b);
    return x.u;
}
__device__ __forceinline__ uint2 pk4rtz(float a, float b, float c, float d) {
    return make_uint2(pk2rtz(a, b), pk2rtz(c, d));
}
__device__ __forceinline__ unsigned pkadd(unsigned hu, unsigned yu) {
    union { f16x2 h; unsigned u; } a, b;
    a.u = hu; b.u = yu;
    a.h = a.h + b.h;            // v_pk_add_f16
    return a.u;
}
__device__ __forceinline__ f16x8 frd(const unsigned short* p) {   // LDS, 8B-aligned
    union { struct { uint2 a, b; } u; f16x8 f; } x;
    x.u.a = *(const uint2*)p;
    x.u.b = *(const uint2*)(p + 4);
    return x.f;
}
__device__ __forceinline__ f16x8 gfrd(const unsigned short* p) {  // global, 16B-aligned
    union { uint4 u; f16x8 f; } x;
    x.u = *(const uint4*)p;
    return x.f;
}

// ---- prep v2: coalesced LDS tile transpose (R13, kept) ----
extern "C" __global__ void idmpnn_prep(const float* __restrict__ w1,
                                       const float* __restrict__ w2,
                                       const float* __restrict__ s1w,
                                       const float* __restrict__ s2w,
                                       char* __restrict__ ws)
{
    __shared__ float tile[64][65];
    unsigned short* wsu = (unsigned short*)ws;
    const int bid = blockIdx.x, t = threadIdx.x;   // 256 threads

    if (bid < 9) {
        const float* src;
        unsigned short* dst;
        if (bid < 4)      { src = w1 + bid * 4096;       dst = wsu + W1F + bid * 4096; }
        else if (bid < 8) { src = w2 + (bid - 4) * 4096; dst = wsu + W2F + (bid - 4) * 4096; }
        else              { src = s1w;                   dst = wsu + S1F; }
#pragma unroll
        for (int k = 0; k < 16; ++k) {
            int lin = k * 256 + t;                 // coalesced read
            tile[lin & 63][lin >> 6] = src[lin];   // tile[c][r] = src[r][c]
        }
        __syncthreads();
#pragma unroll
        for (int k = 0; k < 16; ++k) {
            int lin = k * 256 + t;                 // coalesced write
            union { _Float16 h; unsigned short u; } cv;
            cv.h = (_Float16)tile[lin >> 6][lin & 63];  // RNE
            dst[lin] = cv.u;
        }
    } else if (bid == 9) {
        float* dstf = (float*)(ws + S2WT_BYTE);
#pragma unroll
        for (int k = 0; k < 16; ++k) {
            int lin = k * 256 + t;
            tile[lin & 63][lin >> 6] = s2w[lin];
        }
        __syncthreads();
#pragma unroll
        for (int k = 0; k < 16; ++k) {
            int lin = k * 256 + t;
            dstf[lin] = tile[lin >> 6][lin & 63];
        }
    } else if (bid == 10) {
        unsigned* g = (unsigned*)(ws + GMAX_BYTE);
#pragma unroll
        for (int k = 0; k < 16; ++k) g[k * 256 + t] = 0u;
    } else {
        if (t < 64) ((unsigned*)(ws + CNT_BYTE))[t] = 0u;
    }
}

extern "C" __global__ void __launch_bounds__(192, 2)
idmpnn_main(const int* __restrict__ xg, const float* __restrict__ subadj,
            const int* __restrict__ subgs, const int* __restrict__ num_node,
            const float* __restrict__ idemb, const float* __restrict__ node_emb,
            const float* __restrict__ b1g, const float* __restrict__ b2g,
            const float* __restrict__ lngm, const float* __restrict__ lnbm,
            const float* __restrict__ s1bm, const float* __restrict__ s2bm,
            const float* __restrict__ outw, const float* __restrict__ outb,
            const unsigned short* __restrict__ wsf, const float* __restrict__ s2wt,
            unsigned* __restrict__ gmax, unsigned* __restrict__ cnt,
            float* __restrict__ out)
{
    // 27648 + 768 + 4096 + 256 = 32768 B LDS
    __shared__ unsigned short WB[6 * WBU];   // [perm] HB/GB views + final h
    __shared__ float idS[KSUB * 64];
    __shared__ float prm[NLAYER * 4 * 64];   // b1,b2,g,be per layer
    __shared__ float HSf[HID];

    const int s = blockIdx.x, b = s >> 5;    // one subgraph per block
    const int tid = threadIdx.x;
    const int w = tid / 64, lane = tid & 63; // w = 0..2; wave owns perms 2w,2w+1
    const int c = lane & 15, q = lane >> 4;

    for (int t = tid; t < NLAYER * 4 * 64; t += 192) {
        int l = t >> 8, r2 = t & 255, set = r2 >> 6, d = r2 & 63;
        const float* src = (set == 0) ? b1g : (set == 1) ? b2g : (set == 2) ? lngm : lnbm;
        prm[t] = src[l * HID + d];
    }
    if (tid < KSUB * 64) idS[tid] = idemb[tid];

    const int nd0 = subgs[s * KSUB + 0];
    const int nd1 = subgs[s * KSUB + 1];
    const int nd2 = subgs[s * KSUB + 2];
    const int nn = num_node[b];
    const int zi0 = xg[b * NM + c];
    const int zi1 = xg[b * NM + 16 + c];

    // adjacency fp16 B-frags: lane holds adj[i=in*16+c][j=8q+jj], regs
    f16x8 adjf[2];
#pragma unroll
    for (int in_ = 0; in_ < 2; ++in_) {
        const float* ap = subadj + (size_t)b * NM * NM + (in_ * 16 + c) * NM + 8 * q;
        float4 f0 = *(const float4*)ap;
        float4 f1 = *(const float4*)(ap + 4);
        union { struct { uint2 a, b; } u; f16x8 f; } x;
        x.u.a = pk4rtz(f0.x, f0.y, f0.z, f0.w);
        x.u.b = pk4rtz(f1.x, f1.y, f1.z, f1.w);
        adjf[in_] = x.f;
    }

    __syncthreads();

    // chain ch (0,1) = perm w*2+ch; private buffer per chain
    unsigned short* wbc[2] = { WB + (w * 2 + 0) * WBU, WB + (w * 2 + 1) * WBU };

    // h packed 2xfp16: hpk[ch][in*8+dm*2+g2] = h[i=in*16+c][d=dm*16+4q+2g2+{0,1}]
    unsigned hpk[2][16];
#pragma unroll
    for (int in_ = 0; in_ < 2; ++in_) {
        int i = in_ * 16 + c;
        int z = in_ ? zi1 : zi0;
        int pid[2];
#pragma unroll
        for (int ch = 0; ch < 2; ++ch) {
            int p = w * 2 + ch;
            pid[ch] = (i == nd0) ? c_perm[0][p] : (i == nd1) ? c_perm[1][p]
                      : (i == nd2) ? c_perm[2][p] : -1;
        }
#pragma unroll
        for (int dm = 0; dm < 4; ++dm) {
            float4 e4 = *(const float4*)(node_emb + (size_t)z * HID + dm * 16 + 4 * q);
#pragma unroll
            for (int ch = 0; ch < 2; ++ch) {
                float4 v = e4;
                if (pid[ch] >= 0) {
                    float4 f4 = *(const float4*)&idS[pid[ch] * 64 + dm * 16 + 4 * q];
                    v.x *= f4.x; v.y *= f4.y; v.z *= f4.z; v.w *= f4.w;
                }
                uint2 u = pk4rtz(v.x, v.y, v.z, v.w);
                hpk[ch][in_ * 8 + dm * 2 + 0] = u.x;
                hpk[ch][in_ * 8 + dm * 2 + 1] = u.y;
                // layer-0 h -> HB (in-loop write is fused into the epilogue)
                *(uint2*)(wbc[ch] + i * SH + dm * 16 + 4 * q) = u;
            }
        }
    }

#pragma unroll 1
    for (int l = 0; l < NLAYER; ++l) {
        // (2) GEMM-A A-frags, both chains (HB holds h from init/epilogue)
        f16x8 hah[2][2][2];
#pragma unroll
        for (int ch = 0; ch < 2; ++ch)
#pragma unroll
            for (int im = 0; im < 2; ++im)
#pragma unroll
                for (int ks = 0; ks < 2; ++ks)
                    hah[ch][im][ks] = frd(wbc[ch] + (im * 16 + c) * SH + ks * 32 + 8 * q);

        // (3+4) GEMM-A: g = h @ W1; write GB [d'][i] (weights shared)
#pragma unroll
        for (int jn = 0; jn < 4; ++jn) {
            const unsigned short* wp = wsf + W1F + (l * 64 + jn * 16 + c) * 64;
            f16x8 b0 = gfrd(wp + 8 * q);
            f16x8 b1 = gfrd(wp + 32 + 8 * q);
#pragma unroll
            for (int ch = 0; ch < 2; ++ch) {
                f32x4 g0 = {0.f, 0.f, 0.f, 0.f}, g1 = {0.f, 0.f, 0.f, 0.f};
                g0 = MFMA16(hah[ch][0][0], b0, g0);
                g0 = MFMA16(hah[ch][0][1], b1, g0);
                g1 = MFMA16(hah[ch][1][0], b0, g1);
                g1 = MFMA16(hah[ch][1][1], b1, g1);
                *(uint2*)(wbc[ch] + (jn * 16 + c) * SG + 4 * q)      = pk4rtz(g0[0], g0[1], g0[2], g0[3]);
                *(uint2*)(wbc[ch] + (jn * 16 + c) * SG + 16 + 4 * q) = pk4rtz(g1[0], g1[1], g1[2], g1[3]);
            }
        }

        // (5) GEMM-B A-frags
        f16x8 gah[2][4];
#pragma unroll
        for (int ch = 0; ch < 2; ++ch)
#pragma unroll
            for (int dm = 0; dm < 4; ++dm)
                gah[ch][dm] = frd(wbc[ch] + (dm * 16 + c) * SG + 8 * q);

        // (6+7) GEMM-B: t^T = g^T @ adjT; t -> HB with relu(+b1)
#pragma unroll
        for (int dm = 0; dm < 4; ++dm) {
            float4 b1v = *(const float4*)&prm[(l * 4 + 0) * 64 + dm * 16 + 4 * q];
#pragma unroll
            for (int ch = 0; ch < 2; ++ch) {
                f32x4 t0 = {0.f, 0.f, 0.f, 0.f}, t1 = {0.f, 0.f, 0.f, 0.f};
                t0 = MFMA16(gah[ch][dm], adjf[0], t0);
                t1 = MFMA16(gah[ch][dm], adjf[1], t1);
                *(uint2*)(wbc[ch] + c * SH + dm * 16 + 4 * q) =
                    pk4rtz(fmaxf(t0[0] + b1v.x, 0.f), fmaxf(t0[1] + b1v.y, 0.f),
                           fmaxf(t0[2] + b1v.z, 0.f), fmaxf(t0[3] + b1v.w, 0.f));
                *(uint2*)(wbc[ch] + (16 + c) * SH + dm * 16 + 4 * q) =
                    pk4rtz(fmaxf(t1[0] + b1v.x, 0.f), fmaxf(t1[1] + b1v.y, 0.f),
                           fmaxf(t1[2] + b1v.z, 0.f), fmaxf(t1[3] + b1v.w, 0.f));
            }
        }

        // (8) GEMM-C B-frags (t rows; after this HB is free for new h)
        f16x8 tbh[2][2][2];
#pragma unroll
        for (int ch = 0; ch < 2; ++ch)
#pragma unroll
            for (int in_ = 0; in_ < 2; ++in_)
#pragma unroll
                for (int ks = 0; ks < 2; ++ks)
                    tbh[ch][in_][ks] = frd(wbc[ch] + (in_ * 16 + c) * SH + ks * 32 + 8 * q);

        // (9+10) GEMM-C': u^T = W2^T @ t^T; LN; relu; residual (pk_add);
        //         write new h straight into HB (next layer reads it there)
#pragma unroll
        for (int in_ = 0; in_ < 2; ++in_) {
            float v[2][16];
            float s1[2] = {0.f, 0.f}, s2[2] = {0.f, 0.f};
#pragma unroll
            for (int dm = 0; dm < 4; ++dm) {
                const unsigned short* wp2 = wsf + W2F + (l * 64 + dm * 16 + c) * 64;
                f16x8 a0 = gfrd(wp2 + 8 * q);
                f16x8 a1 = gfrd(wp2 + 32 + 8 * q);
                float4 b2v = *(const float4*)&prm[(l * 4 + 1) * 64 + dm * 16 + 4 * q];
                const float* bb = (const float*)&b2v;
#pragma unroll
                for (int ch = 0; ch < 2; ++ch) {
                    f32x4 u = {0.f, 0.f, 0.f, 0.f};
                    u = MFMA16(a0, tbh[ch][in_][0], u);
                    u = MFMA16(a1, tbh[ch][in_][1], u);
#pragma unroll
                    for (int r = 0; r < 4; ++r) {
                        float x = u[r] + bb[r];
                        v[ch][dm * 4 + r] = x;
                        s1[ch] += x;
                        s2[ch] += x * x;
                    }
                }
            }
#pragma unroll
            for (int ch = 0; ch < 2; ++ch) {
                float a1 = s1[ch], a2 = s2[ch];
                a1 += __shfl_xor(a1, 16, 64); a1 += __shfl_xor(a1, 32, 64);
                a2 += __shfl_xor(a2, 16, 64); a2 += __shfl_xor(a2, 32, 64);
                float mean = a1 * (1.0f / HID);
                float var  = a2 * (1.0f / HID) - mean * mean;
                float rs   = rsqrtf(var + 1e-5f);
#pragma unroll
                for (int dm = 0; dm < 4; ++dm) {
                    float4 gv4  = *(const float4*)&prm[(l * 4 + 2) * 64 + dm * 16 + 4 * q];
                    float4 bev4 = *(const float4*)&prm[(l * 4 + 3) * 64 + dm * 16 + 4 * q];
                    const float* gp = (const float*)&gv4;
                    const float* bp = (const float*)&bev4;
                    float y0 = fmaxf((v[ch][dm * 4 + 0] - mean) * rs * gp[0] + bp[0], 0.f);
                    float y1 = fmaxf((v[ch][dm * 4 + 1] - mean) * rs * gp[1] + bp[1], 0.f);
                    float y2 = fmaxf((v[ch][dm * 4 + 2] - mean) * rs * gp[2] + bp[2], 0.f);
                    float y3 = fmaxf((v[ch][dm * 4 + 3] - mean) * rs * gp[3] + bp[3], 0.f);
                    int i0 = in_ * 8 + dm * 2;
                    unsigned n0 = pkadd(hpk[ch][i0 + 0], pk2rtz(y0, y1));
                    unsigned n1 = pkadd(hpk[ch][i0 + 1], pk2rtz(y2, y3));
                    hpk[ch][i0 + 0] = n0;
                    hpk[ch][i0 + 1] = n1;
                    *(uint2*)(wbc[ch] + (in_ * 16 + c) * SH + dm * 16 + 4 * q) =
                        make_uint2(n0, n1);
                }
            }
        }
    }
    // HB already holds final h per chain (written by last epilogue)
    __syncthreads();

    // ---- tail (wave 0): combine 6 perms, GEMM-D, colsum, set2, pooling ----
    if (w == 0) {
        f16x8 mah[2][2];
#pragma unroll
        for (int im = 0; im < 2; ++im) {
            float sc = ((im * 16 + c) < nn) ? (1.0f / PP) : 0.f;
#pragma unroll
            for (int ks = 0; ks < 2; ++ks) {
                int ro = (im * 16 + c) * SH + ks * 32 + 8 * q;
                float acc8[8];
#pragma unroll
                for (int j = 0; j < 8; ++j) acc8[j] = 0.f;
#pragma unroll
                for (int pv = 0; pv < 6; ++pv) {
                    f16x8 f = frd(WB + pv * WBU + ro);
#pragma unroll
                    for (int j = 0; j < 8; ++j) acc8[j] += (float)f[j];
                }
                f16x8 m;
#pragma unroll
                for (int j = 0; j < 8; ++j) m[j] = (_Float16)(acc8[j] * sc);
                mah[im][ks] = m;
            }
        }

        // GEMM-D: h1 = hm @ set1_W (m=i, n=dout)
        f32x4 hh[2][4];
#pragma unroll
        for (int im = 0; im < 2; ++im)
#pragma unroll
            for (int jn = 0; jn < 4; ++jn) hh[im][jn] = (f32x4){0.f, 0.f, 0.f, 0.f};
#pragma unroll
        for (int jn = 0; jn < 4; ++jn) {
            const unsigned short* sp = wsf + S1F + (jn * 16 + c) * 64;
            f16x8 b0 = gfrd(sp + 8 * q);
            f16x8 b1 = gfrd(sp + 32 + 8 * q);
#pragma unroll
            for (int im = 0; im < 2; ++im) {
                hh[im][jn] = MFMA16(mah[im][0], b0, hh[im][jn]);
                hh[im][jn] = MFMA16(mah[im][1], b1, hh[im][jn]);
            }
        }
        // colsum over all 32 rows (padded rows contribute relu(s1b), as ref)
#pragma unroll
        for (int jn = 0; jn < 4; ++jn) {
            float sb = s1bm[jn * 16 + c];
            float cs = 0.f;
#pragma unroll
            for (int im = 0; im < 2; ++im)
#pragma unroll
                for (int r = 0; r < 4; ++r)
                    cs += fmaxf(hh[im][jn][r] + sb, 0.f);
            cs += __shfl_xor(cs, 16, 64);
            cs += __shfl_xor(cs, 32, 64);
            if (q == 0) HSf[jn * 16 + c] = cs;
        }

        // h2 = relu(HS @ set2_W + s2b), lane = dout
        float acc = 0.f;
#pragma unroll
        for (int e4 = 0; e4 < 16; ++e4) {
            float4 wv = *(const float4*)&s2wt[lane * 64 + e4 * 4];
            float4 hv = *(const float4*)&HSf[e4 * 4];
            acc += hv.x * wv.x + hv.y * wv.y + hv.z * wv.z + hv.w * wv.w;
        }
        float h2 = fmaxf(acc + s2bm[lane], 0.f);

        // pooling fold: device-scope atomicMax (h2 >= 0: uint order == float order)
        atomicMax(&gmax[b * HID + lane], __float_as_uint(h2));
        __threadfence();
        unsigned old = 0;
        if (lane == 0) old = atomicAdd(&cnt[b], 1u);
        old = __shfl(old, 0, 64);
        if (old == NS - 1) {   // last of the 32 subgraph-writers of this graph
            __threadfence();
            unsigned mbits = atomicOr(&gmax[b * HID + lane], 0u);
            float v = __uint_as_float(mbits) * outw[lane];
#pragma unroll
            for (int off = 32; off > 0; off >>= 1) v += __shfl_xor(v, off, 64);
            if (lane == 0) out[b] = v + outb[0];
        }
    }
}

extern "C" void kernel_launch(void* const* d_in, const int* in_sizes, int n_in,
                              void* d_out, int out_size, void* d_ws, size_t ws_size,
                              hipStream_t stream)
{
    const int*   xg       = (const int*)d_in[0];
    const float* subadj   = (const float*)d_in[1];
    const int*   subgs    = (const int*)d_in[2];
    const int*   num_node = (const int*)d_in[3];
    const float* idemb    = (const float*)d_in[5];
    const float* node_emb = (const float*)d_in[6];
    const float* w1       = (const float*)d_in[7];
    const float* b1       = (const float*)d_in[8];
    const float* w2       = (const float*)d_in[9];
    const float* b2       = (const float*)d_in[10];
    const float* g        = (const float*)d_in[11];
    const float* be       = (const float*)d_in[12];
    const float* s1w      = (const float*)d_in[13];
    const float* s1b      = (const float*)d_in[14];
    const float* s2w      = (const float*)d_in[15];
    const float* s2b      = (const float*)d_in[16];
    const float* outw     = (const float*)d_in[17];
    const float* outb     = (const float*)d_in[18];

    char* ws = (char*)d_ws;
    unsigned short* wsf = (unsigned short*)ws;
    const float* s2wt = (const float*)(ws + S2WT_BYTE);
    unsigned* gmax = (unsigned*)(ws + GMAX_BYTE);
    unsigned* cnt  = (unsigned*)(ws + CNT_BYTE);

    idmpnn_prep<<<12, 256, 0, stream>>>(w1, w2, s1w, s2w, ws);
    idmpnn_main<<<STOT, 192, 0, stream>>>(xg, subadj, subgs, num_node,
                                          idemb, node_emb,
                                          b1, b2, g, be, s1b, s2b, outw, outb,
                                          wsf, s2wt, gmax, cnt, (float*)d_out);
}

// Round 16
// 200.533 us; speedup vs baseline: 1.1816x; 1.0389x over previous
//
#include <hip/hip_runtime.h>
#include <math.h>

// IDMPNN fused forward — R16 = R13 verbatim (best: bench 199.7us, main ~133us).
// R15's two trims (pkadd residual + epilogue-fused HB write) regressed 133->147
// and are reverted. Final structure: block = 192 thr (3 waves) = one subgraph;
// wave w runs perms {2w,2w+1} as 2 interleaved ILP chains with private 4608B
// LDS buffers; K32 fp16 MFMA chain g=h@W1 -> t^T=g^T@adjT -> u^T=W2^T@t^T with
// producer-M==consumer-K orientation (contiguous relayouts); fp16-packed
// residual in 32 VGPRs; fused tail + device-atomic segment-max; coalesced
// tile-transpose prep. Burned-in lessons: min-waves>=3 always spills (needs
// ~116 arch VGPRs); K16 zero-LDS loses (2x MFMA issue); plateau is
// latency-bound at ~5 waves/CU, not a pipe roofline.

#define NBATCH 64
#define NM 32
#define NS 32
#define KSUB 3
#define HID 64
#define NLAYER 4
#define PP 6
#define STOT (NBATCH * NS)

// d_ws: fp16 weight planes (ushort offsets), then byte offsets
#define W1F 0            // [l][dout][din] 16384
#define W2F 16384
#define S1F 32768        // planes end at ushort 36864 = byte 73728
#define GMAX_BYTE 73728  // uint[64*64]
#define CNT_BYTE  90112  // uint[64]
#define S2WT_BYTE 90368  // float[64*64]

// LDS row strides (ushorts)
#define SH 68    // HB rows (32 x 64 fp16 + pad)
#define SG 36    // GB rows (64 x 32 fp16 + pad)
#define WBU 2304 // per-chain buffer ushorts (4608B): max(32*68, 64*36)

typedef _Float16 f16x8 __attribute__((ext_vector_type(8)));
typedef __fp16 fp16x2 __attribute__((ext_vector_type(2)));   // cvt_pkrtz return
typedef float f32x4 __attribute__((ext_vector_type(4)));

#define MFMA16(a, b, c) __builtin_amdgcn_mfma_f32_16x16x32_f16(a, b, c, 0, 0, 0)

__constant__ int c_perm[KSUB][PP] = {
    {0, 0, 1, 1, 2, 2},
    {1, 2, 0, 2, 0, 1},
    {2, 1, 2, 0, 1, 0}
};

__device__ __forceinline__ unsigned pk2rtz(float a, float b) {
    union { fp16x2 h; unsigned u; } x;
    x.h = __builtin_amdgcn_cvt_pkrtz(a, b);
    return x.u;
}
__device__ __forceinline__ uint2 pk4rtz(float a, float b, float c, float d) {
    return make_uint2(pk2rtz(a, b), pk2rtz(c, d));
}
__device__ __forceinline__ f16x8 frd(const unsigned short* p) {   // LDS, 8B-aligned
    union { struct { uint2 a, b; } u; f16x8 f; } x;
    x.u.a = *(const uint2*)p;
    x.u.b = *(const uint2*)(p + 4);
    return x.f;
}
__device__ __forceinline__ f16x8 gfrd(const unsigned short* p) {  // global, 16B-aligned
    union { uint4 u; f16x8 f; } x;
    x.u = *(const uint4*)p;
    return x.f;
}
__device__ __forceinline__ float2 upk2(unsigned u) {
    union { unsigned u; _Float16 h[2]; } x; x.u = u;
    return make_float2((float)x.h[0], (float)x.h[1]);
}

// ---- prep: coalesced LDS tile transpose ----
// blocks 0-3: W1[l] -> [dout][din] fp16; 4-7: W2[l]; 8: set1_W; 9: s2w^T f32;
// 10: zero gmax; 11: zero cnt.
extern "C" __global__ void idmpnn_prep(const float* __restrict__ w1,
                                       const float* __restrict__ w2,
                                       const float* __restrict__ s1w,
                                       const float* __restrict__ s2w,
                                       char* __restrict__ ws)
{
    __shared__ float tile[64][65];
    unsigned short* wsu = (unsigned short*)ws;
    const int bid = blockIdx.x, t = threadIdx.x;   // 256 threads

    if (bid < 9) {
        const float* src;
        unsigned short* dst;
        if (bid < 4)      { src = w1 + bid * 4096;       dst = wsu + W1F + bid * 4096; }
        else if (bid < 8) { src = w2 + (bid - 4) * 4096; dst = wsu + W2F + (bid - 4) * 4096; }
        else              { src = s1w;                   dst = wsu + S1F; }
#pragma unroll
        for (int k = 0; k < 16; ++k) {
            int lin = k * 256 + t;                 // coalesced read
            tile[lin & 63][lin >> 6] = src[lin];   // tile[c][r] = src[r][c]
        }
        __syncthreads();
#pragma unroll
        for (int k = 0; k < 16; ++k) {
            int lin = k * 256 + t;                 // coalesced write
            union { _Float16 h; unsigned short u; } cv;
            cv.h = (_Float16)tile[lin >> 6][lin & 63];  // RNE
            dst[lin] = cv.u;
        }
    } else if (bid == 9) {
        float* dstf = (float*)(ws + S2WT_BYTE);
#pragma unroll
        for (int k = 0; k < 16; ++k) {
            int lin = k * 256 + t;
            tile[lin & 63][lin >> 6] = s2w[lin];
        }
        __syncthreads();
#pragma unroll
        for (int k = 0; k < 16; ++k) {
            int lin = k * 256 + t;
            dstf[lin] = tile[lin >> 6][lin & 63];
        }
    } else if (bid == 10) {
        unsigned* g = (unsigned*)(ws + GMAX_BYTE);
#pragma unroll
        for (int k = 0; k < 16; ++k) g[k * 256 + t] = 0u;
    } else {
        if (t < 64) ((unsigned*)(ws + CNT_BYTE))[t] = 0u;
    }
}

extern "C" __global__ void __launch_bounds__(192, 2)
idmpnn_main(const int* __restrict__ xg, const float* __restrict__ subadj,
            const int* __restrict__ subgs, const int* __restrict__ num_node,
            const float* __restrict__ idemb, const float* __restrict__ node_emb,
            const float* __restrict__ b1g, const float* __restrict__ b2g,
            const float* __restrict__ lngm, const float* __restrict__ lnbm,
            const float* __restrict__ s1bm, const float* __restrict__ s2bm,
            const float* __restrict__ outw, const float* __restrict__ outb,
            const unsigned short* __restrict__ wsf, const float* __restrict__ s2wt,
            unsigned* __restrict__ gmax, unsigned* __restrict__ cnt,
            float* __restrict__ out)
{
    // 27648 + 768 + 4096 + 256 = 32768 B LDS
    __shared__ unsigned short WB[6 * WBU];   // [perm] HB/GB views + final dump
    __shared__ float idS[KSUB * 64];
    __shared__ float prm[NLAYER * 4 * 64];   // b1,b2,g,be per layer
    __shared__ float HSf[HID];

    const int s = blockIdx.x, b = s >> 5;    // one subgraph per block
    const int tid = threadIdx.x;
    const int w = tid / 64, lane = tid & 63; // w = 0..2; wave owns perms 2w,2w+1
    const int c = lane & 15, q = lane >> 4;

    for (int t = tid; t < NLAYER * 4 * 64; t += 192) {
        int l = t >> 8, r2 = t & 255, set = r2 >> 6, d = r2 & 63;
        const float* src = (set == 0) ? b1g : (set == 1) ? b2g : (set == 2) ? lngm : lnbm;
        prm[t] = src[l * HID + d];
    }
    if (tid < KSUB * 64) idS[tid] = idemb[tid];

    const int nd0 = subgs[s * KSUB + 0];
    const int nd1 = subgs[s * KSUB + 1];
    const int nd2 = subgs[s * KSUB + 2];
    const int nn = num_node[b];
    const int zi0 = xg[b * NM + c];
    const int zi1 = xg[b * NM + 16 + c];

    // adjacency fp16 B-frags: lane holds adj[i=in*16+c][j=8q+jj], regs
    f16x8 adjf[2];
#pragma unroll
    for (int in_ = 0; in_ < 2; ++in_) {
        const float* ap = subadj + (size_t)b * NM * NM + (in_ * 16 + c) * NM + 8 * q;
        float4 f0 = *(const float4*)ap;
        float4 f1 = *(const float4*)(ap + 4);
        union { struct { uint2 a, b; } u; f16x8 f; } x;
        x.u.a = pk4rtz(f0.x, f0.y, f0.z, f0.w);
        x.u.b = pk4rtz(f1.x, f1.y, f1.z, f1.w);
        adjf[in_] = x.f;
    }

    __syncthreads();

    // chain ch (0,1) = perm w*2+ch; private buffer per chain
    unsigned short* wbc[2] = { WB + (w * 2 + 0) * WBU, WB + (w * 2 + 1) * WBU };

    // h packed 2xfp16: hpk[ch][in*8+dm*2+g2] = h[i=in*16+c][d=dm*16+4q+2g2+{0,1}]
    unsigned hpk[2][16];
#pragma unroll
    for (int in_ = 0; in_ < 2; ++in_) {
        int i = in_ * 16 + c;
        int z = in_ ? zi1 : zi0;
        int pid[2];
#pragma unroll
        for (int ch = 0; ch < 2; ++ch) {
            int p = w * 2 + ch;
            pid[ch] = (i == nd0) ? c_perm[0][p] : (i == nd1) ? c_perm[1][p]
                      : (i == nd2) ? c_perm[2][p] : -1;
        }
#pragma unroll
        for (int dm = 0; dm < 4; ++dm) {
            float4 e4 = *(const float4*)(node_emb + (size_t)z * HID + dm * 16 + 4 * q);
#pragma unroll
            for (int ch = 0; ch < 2; ++ch) {
                float4 v = e4;
                if (pid[ch] >= 0) {
                    float4 f4 = *(const float4*)&idS[pid[ch] * 64 + dm * 16 + 4 * q];
                    v.x *= f4.x; v.y *= f4.y; v.z *= f4.z; v.w *= f4.w;
                }
                uint2 u = pk4rtz(v.x, v.y, v.z, v.w);
                hpk[ch][in_ * 8 + dm * 2 + 0] = u.x;
                hpk[ch][in_ * 8 + dm * 2 + 1] = u.y;
            }
        }
    }

#pragma unroll 1
    for (int l = 0; l < NLAYER; ++l) {
        // (1) h -> HB [i][d], both chains
#pragma unroll
        for (int ch = 0; ch < 2; ++ch)
#pragma unroll
            for (int in_ = 0; in_ < 2; ++in_)
#pragma unroll
                for (int dm = 0; dm < 4; ++dm)
                    *(uint2*)(wbc[ch] + (in_ * 16 + c) * SH + dm * 16 + 4 * q) =
                        make_uint2(hpk[ch][in_ * 8 + dm * 2], hpk[ch][in_ * 8 + dm * 2 + 1]);

        // (2) GEMM-A A-frags, both chains
        f16x8 hah[2][2][2];
#pragma unroll
        for (int ch = 0; ch < 2; ++ch)
#pragma unroll
            for (int im = 0; im < 2; ++im)
#pragma unroll
                for (int ks = 0; ks < 2; ++ks)
                    hah[ch][im][ks] = frd(wbc[ch] + (im * 16 + c) * SH + ks * 32 + 8 * q);

        // (3+4) GEMM-A: g = h @ W1; write GB [d'][i] (weights shared)
#pragma unroll
        for (int jn = 0; jn < 4; ++jn) {
            const unsigned short* wp = wsf + W1F + (l * 64 + jn * 16 + c) * 64;
            f16x8 b0 = gfrd(wp + 8 * q);
            f16x8 b1 = gfrd(wp + 32 + 8 * q);
#pragma unroll
            for (int ch = 0; ch < 2; ++ch) {
                f32x4 g0 = {0.f, 0.f, 0.f, 0.f}, g1 = {0.f, 0.f, 0.f, 0.f};
                g0 = MFMA16(hah[ch][0][0], b0, g0);
                g0 = MFMA16(hah[ch][0][1], b1, g0);
                g1 = MFMA16(hah[ch][1][0], b0, g1);
                g1 = MFMA16(hah[ch][1][1], b1, g1);
                *(uint2*)(wbc[ch] + (jn * 16 + c) * SG + 4 * q)      = pk4rtz(g0[0], g0[1], g0[2], g0[3]);
                *(uint2*)(wbc[ch] + (jn * 16 + c) * SG + 16 + 4 * q) = pk4rtz(g1[0], g1[1], g1[2], g1[3]);
            }
        }

        // (5) GEMM-B A-frags
        f16x8 gah[2][4];
#pragma unroll
        for (int ch = 0; ch < 2; ++ch)
#pragma unroll
            for (int dm = 0; dm < 4; ++dm)
                gah[ch][dm] = frd(wbc[ch] + (dm * 16 + c) * SG + 8 * q);

        // (6+7) GEMM-B: t^T = g^T @ adjT; t -> HB with relu(+b1)
#pragma unroll
        for (int dm = 0; dm < 4; ++dm) {
            float4 b1v = *(const float4*)&prm[(l * 4 + 0) * 64 + dm * 16 + 4 * q];
#pragma unroll
            for (int ch = 0; ch < 2; ++ch) {
                f32x4 t0 = {0.f, 0.f, 0.f, 0.f}, t1 = {0.f, 0.f, 0.f, 0.f};
                t0 = MFMA16(gah[ch][dm], adjf[0], t0);
                t1 = MFMA16(gah[ch][dm], adjf[1], t1);
                *(uint2*)(wbc[ch] + c * SH + dm * 16 + 4 * q) =
                    pk4rtz(fmaxf(t0[0] + b1v.x, 0.f), fmaxf(t0[1] + b1v.y, 0.f),
                           fmaxf(t0[2] + b1v.z, 0.f), fmaxf(t0[3] + b1v.w, 0.f));
                *(uint2*)(wbc[ch] + (16 + c) * SH + dm * 16 + 4 * q) =
                    pk4rtz(fmaxf(t1[0] + b1v.x, 0.f), fmaxf(t1[1] + b1v.y, 0.f),
                           fmaxf(t1[2] + b1v.z, 0.f), fmaxf(t1[3] + b1v.w, 0.f));
            }
        }

        // (8) GEMM-C B-frags
        f16x8 tbh[2][2][2];
#pragma unroll
        for (int ch = 0; ch < 2; ++ch)
#pragma unroll
            for (int in_ = 0; in_ < 2; ++in_)
#pragma unroll
                for (int ks = 0; ks < 2; ++ks)
                    tbh[ch][in_][ks] = frd(wbc[ch] + (in_ * 16 + c) * SH + ks * 32 + 8 * q);

        // (9+10) GEMM-C': u^T = W2^T @ t^T; LN; relu; residual
#pragma unroll
        for (int in_ = 0; in_ < 2; ++in_) {
            float v[2][16];
            float s1[2] = {0.f, 0.f}, s2[2] = {0.f, 0.f};
#pragma unroll
            for (int dm = 0; dm < 4; ++dm) {
                const unsigned short* wp2 = wsf + W2F + (l * 64 + dm * 16 + c) * 64;
                f16x8 a0 = gfrd(wp2 + 8 * q);
                f16x8 a1 = gfrd(wp2 + 32 + 8 * q);
                float4 b2v = *(const float4*)&prm[(l * 4 + 1) * 64 + dm * 16 + 4 * q];
                const float* bb = (const float*)&b2v;
#pragma unroll
                for (int ch = 0; ch < 2; ++ch) {
                    f32x4 u = {0.f, 0.f, 0.f, 0.f};
                    u = MFMA16(a0, tbh[ch][in_][0], u);
                    u = MFMA16(a1, tbh[ch][in_][1], u);
#pragma unroll
                    for (int r = 0; r < 4; ++r) {
                        float x = u[r] + bb[r];
                        v[ch][dm * 4 + r] = x;
                        s1[ch] += x;
                        s2[ch] += x * x;
                    }
                }
            }
#pragma unroll
            for (int ch = 0; ch < 2; ++ch) {
                float a1 = s1[ch], a2 = s2[ch];
                a1 += __shfl_xor(a1, 16, 64); a1 += __shfl_xor(a1, 32, 64);
                a2 += __shfl_xor(a2, 16, 64); a2 += __shfl_xor(a2, 32, 64);
                float mean = a1 * (1.0f / HID);
                float var  = a2 * (1.0f / HID) - mean * mean;
                float rs   = rsqrtf(var + 1e-5f);
#pragma unroll
                for (int dm = 0; dm < 4; ++dm) {
                    float4 gv4  = *(const float4*)&prm[(l * 4 + 2) * 64 + dm * 16 + 4 * q];
                    float4 bev4 = *(const float4*)&prm[(l * 4 + 3) * 64 + dm * 16 + 4 * q];
                    const float* gp = (const float*)&gv4;
                    const float* bp = (const float*)&bev4;
                    float y0 = fmaxf((v[ch][dm * 4 + 0] - mean) * rs * gp[0] + bp[0], 0.f);
                    float y1 = fmaxf((v[ch][dm * 4 + 1] - mean) * rs * gp[1] + bp[1], 0.f);
                    float y2 = fmaxf((v[ch][dm * 4 + 2] - mean) * rs * gp[2] + bp[2], 0.f);
                    float y3 = fmaxf((v[ch][dm * 4 + 3] - mean) * rs * gp[3] + bp[3], 0.f);
                    int i0 = in_ * 8 + dm * 2;
                    float2 h0 = upk2(hpk[ch][i0 + 0]);
                    float2 h1 = upk2(hpk[ch][i0 + 1]);
                    hpk[ch][i0 + 0] = pk2rtz(h0.x + y0, h0.y + y1);
                    hpk[ch][i0 + 1] = pk2rtz(h1.x + y2, h1.y + y3);
                }
            }
        }
    }

    // ---- dump final h (fp16 [i][d]) into per-chain buffers ----
#pragma unroll
    for (int ch = 0; ch < 2; ++ch)
#pragma unroll
        for (int in_ = 0; in_ < 2; ++in_)
#pragma unroll
            for (int dm = 0; dm < 4; ++dm)
                *(uint2*)(wbc[ch] + (in_ * 16 + c) * SH + dm * 16 + 4 * q) =
                    make_uint2(hpk[ch][in_ * 8 + dm * 2], hpk[ch][in_ * 8 + dm * 2 + 1]);
    __syncthreads();

    // ---- tail (wave 0): combine 6 perms, GEMM-D, colsum, set2, pooling ----
    if (w == 0) {
        f16x8 mah[2][2];
#pragma unroll
        for (int im = 0; im < 2; ++im) {
            float sc = ((im * 16 + c) < nn) ? (1.0f / PP) : 0.f;
#pragma unroll
            for (int ks = 0; ks < 2; ++ks) {
                int ro = (im * 16 + c) * SH + ks * 32 + 8 * q;
                float acc8[8];
#pragma unroll
                for (int j = 0; j < 8; ++j) acc8[j] = 0.f;
#pragma unroll
                for (int pv = 0; pv < 6; ++pv) {
                    f16x8 f = frd(WB + pv * WBU + ro);
#pragma unroll
                    for (int j = 0; j < 8; ++j) acc8[j] += (float)f[j];
                }
                f16x8 m;
#pragma unroll
                for (int j = 0; j < 8; ++j) m[j] = (_Float16)(acc8[j] * sc);
                mah[im][ks] = m;
            }
        }

        // GEMM-D: h1 = hm @ set1_W (m=i, n=dout)
        f32x4 hh[2][4];
#pragma unroll
        for (int im = 0; im < 2; ++im)
#pragma unroll
            for (int jn = 0; jn < 4; ++jn) hh[im][jn] = (f32x4){0.f, 0.f, 0.f, 0.f};
#pragma unroll
        for (int jn = 0; jn < 4; ++jn) {
            const unsigned short* sp = wsf + S1F + (jn * 16 + c) * 64;
            f16x8 b0 = gfrd(sp + 8 * q);
            f16x8 b1 = gfrd(sp + 32 + 8 * q);
#pragma unroll
            for (int im = 0; im < 2; ++im) {
                hh[im][jn] = MFMA16(mah[im][0], b0, hh[im][jn]);
                hh[im][jn] = MFMA16(mah[im][1], b1, hh[im][jn]);
            }
        }
        // colsum over all 32 rows (padded rows contribute relu(s1b), as ref)
#pragma unroll
        for (int jn = 0; jn < 4; ++jn) {
            float sb = s1bm[jn * 16 + c];
            float cs = 0.f;
#pragma unroll
            for (int im = 0; im < 2; ++im)
#pragma unroll
                for (int r = 0; r < 4; ++r)
                    cs += fmaxf(hh[im][jn][r] + sb, 0.f);
            cs += __shfl_xor(cs, 16, 64);
            cs += __shfl_xor(cs, 32, 64);
            if (q == 0) HSf[jn * 16 + c] = cs;
        }

        // h2 = relu(HS @ set2_W + s2b), lane = dout
        float acc = 0.f;
#pragma unroll
        for (int e4 = 0; e4 < 16; ++e4) {
            float4 wv = *(const float4*)&s2wt[lane * 64 + e4 * 4];
            float4 hv = *(const float4*)&HSf[e4 * 4];
            acc += hv.x * wv.x + hv.y * wv.y + hv.z * wv.z + hv.w * wv.w;
        }
        float h2 = fmaxf(acc + s2bm[lane], 0.f);

        // pooling fold: device-scope atomicMax (h2 >= 0: uint order == float order)
        atomicMax(&gmax[b * HID + lane], __float_as_uint(h2));
        __threadfence();
        unsigned old = 0;
        if (lane == 0) old = atomicAdd(&cnt[b], 1u);
        old = __shfl(old, 0, 64);
        if (old == NS - 1) {   // last of the 32 subgraph-writers of this graph
            __threadfence();
            unsigned mbits = atomicOr(&gmax[b * HID + lane], 0u);
            float v = __uint_as_float(mbits) * outw[lane];
#pragma unroll
            for (int off = 32; off > 0; off >>= 1) v += __shfl_xor(v, off, 64);
            if (lane == 0) out[b] = v + outb[0];
        }
    }
}

extern "C" void kernel_launch(void* const* d_in, const int* in_sizes, int n_in,
                              void* d_out, int out_size, void* d_ws, size_t ws_size,
                              hipStream_t stream)
{
    const int*   xg       = (const int*)d_in[0];
    const float* subadj   = (const float*)d_in[1];
    const int*   subgs    = (const int*)d_in[2];
    const int*   num_node = (const int*)d_in[3];
    const float* idemb    = (const float*)d_in[5];
    const float* node_emb = (const float*)d_in[6];
    const float* w1       = (const float*)d_in[7];
    const float* b1       = (const float*)d_in[8];
    const float* w2       = (const float*)d_in[9];
    const float* b2       = (const float*)d_in[10];
    const float* g        = (const float*)d_in[11];
    const float* be       = (const float*)d_in[12];
    const float* s1w      = (const float*)d_in[13];
    const float* s1b      = (const float*)d_in[14];
    const float* s2w      = (const float*)d_in[15];
    const float* s2b      = (const float*)d_in[16];
    const float* outw     = (const float*)d_in[17];
    const float* outb     = (const float*)d_in[18];

    char* ws = (char*)d_ws;
    unsigned short* wsf = (unsigned short*)ws;
    const float* s2wt = (const float*)(ws + S2WT_BYTE);
    unsigned* gmax = (unsigned*)(ws + GMAX_BYTE);
    unsigned* cnt  = (unsigned*)(ws + CNT_BYTE);

    idmpnn_prep<<<12, 256, 0, stream>>>(w1, w2, s1w, s2w, ws);
    idmpnn_main<<<STOT, 192, 0, stream>>>(xg, subadj, subgs, num_node,
                                          idemb, node_emb,
                                          b1, b2, g, be, s1b, s2b, outw, outb,
                                          wsf, s2wt, gmax, cnt, (float*)d_out);
}